// Round 4
// baseline (402.868 us; speedup 1.0000x reference)
//
#include <hip/hip_runtime.h>
#include <hip/hip_bf16.h>

// LinearAttention fused pipeline for MI355X (gfx950), bf16 MFMA.
// B=8, C=512, L=8192, H=8, DH=64, HID=512, M1=3*HID=1536.
// R3: fused QKV+ctx, BK=32 double-buffer (48.5 KiB LDS -> 2 blocks/CU),
// group-ordered block mapping for L2 panel reuse, split-l ctx epilogue.

typedef short short8 __attribute__((ext_vector_type(8)));
typedef short short4v __attribute__((ext_vector_type(4)));
typedef float f32x4 __attribute__((ext_vector_type(4)));
typedef unsigned short ushort;

#define SQRT512 22.627416997969522f

__device__ __forceinline__ ushort f2bf(float f){
  union{float f; unsigned u;} v; v.f = f;
  unsigned r = v.u + 0x7fffu + ((v.u >> 16) & 1u);
  return (ushort)(r >> 16);
}

// async global->LDS, 16B per lane; lds dest is wave-uniform base (HW adds lane*16)
__device__ __forceinline__ void gload16(const void* g, void* l){
  __builtin_amdgcn_global_load_lds(
      (const __attribute__((address_space(1))) unsigned int*)(unsigned long long)g,
      (__attribute__((address_space(3))) unsigned int*)(unsigned int)(unsigned long long)l,
      16, 0, 0);
}

// ---------------- K0b: W1[o][c] = w_qkv[o][c] * g1[c] * sqrt(512)  (bf16) ----------------
__global__ void k_prep_w1(const float* __restrict__ wqkv, const float* __restrict__ g1,
                          ushort* __restrict__ W1){
  int i = blockIdx.x * 256 + threadIdx.x;   // 1536*512 exact
  int c = i & 511;
  W1[i] = f2bf(wqkv[i] * g1[c] * SQRT512);
}

// ---------------- K0: transpose x -> Xt[b][l][c] bf16, and invnorm[b][l] ------------------
__global__ __launch_bounds__(256) void k_xt(const float* __restrict__ x,
                                            ushort* __restrict__ Xt,
                                            float* __restrict__ invnorm){
  __shared__ __align__(16) ushort tile[64*132]; // 64 l-rows x 128 c, pitch 132
  __shared__ float ssq[4][64];
  int b = blockIdx.y, lb = blockIdx.x;
  int t = threadIdx.x, lane = t & 63, crow = t >> 6;
  const float* xb = x + ((size_t)b*512)*8192 + (size_t)lb*64;
  float acc = 0.f;
  for(int c0 = 0; c0 < 512; c0 += 128){
    __syncthreads();
    for(int cc = crow; cc < 128; cc += 4){
      float v = xb[(size_t)(c0+cc)*8192 + lane];
      acc += v*v;
      tile[lane*132 + cc] = f2bf(v);
    }
    __syncthreads();
    ushort* dst = Xt + ((size_t)(b*8192 + lb*64))*512 + c0;
    int ch = t & 31;
    for(int r = t >> 5; r < 64; r += 8){
      short4v vv = *(const short4v*)&tile[r*132 + ch*4];
      *(short4v*)(dst + (size_t)r*512 + ch*4) = vv;
    }
  }
  ssq[crow][lane] = acc;
  __syncthreads();
  if(t < 64){
    float s = ssq[0][t] + ssq[1][t] + ssq[2][t] + ssq[3][t];
    invnorm[b*8192 + lb*64 + t] = 1.f / fmaxf(sqrtf(s), 1e-12f);
  }
}

// ---------------- K1: fused QKV GEMM + q-softmax + exp(k) + ctx partials ------------------
// 512 threads / 8 waves, BK=32, double-buffered 2-phase, 2 blocks/CU.
// Per 256-col panel group g: 4 Q blocks (r=0..3, tile 128x256) + 8 KV blocks
// (ct=2g..2g+1, hb=0..3, tile 256x128: 128 K-rows + 128 V-rows of head-pair hb).
// KV epilogue computes ctx = expK @ V^T (K=128, in two 64-l passes).
__global__ __launch_bounds__(512,4) void k_qkv(
    const ushort* __restrict__ W1, const ushort* __restrict__ Xt,
    const float* __restrict__ invnorm,
    ushort* __restrict__ Qt, float* __restrict__ ctxp, float* __restrict__ kpart){
  __shared__ __align__(16) union U {
    ushort buf[2][12288];                              // 2 x 24 KiB
    struct { ushort P[8192]; ushort Vb[8192]; } e;     // KV epilogue staging (32 KiB)
  } S;
  __shared__ float ksum[128];

  int bid = blockIdx.x;                    // 3072
  int wg  = (bid & 7)*384 + (bid >> 3);    // XCD-contiguous: one batch per XCD
  int b   = wg / 384;
  int rem = wg % 384;
  int grp = rem / 12, s = rem % 12;        // group = one 256-col Xt panel
  bool isQ = (s < 4);
  int t = threadIdx.x, lane = t & 63, w = t >> 6;
  int rsub = lane >> 2;                    // 0..15 row within 16-row staging group
  int pc   = (lane & 3) ^ ((lane >> 3) & 3); // pre-swizzled source chunk (4x16B/row)

  int r = 0, ct2 = 0, hb = 0, ct = 0;
  const ushort* Aq = W1;
  const ushort* Bbase;
  if(isQ){ r = s; ct2 = grp;
    Aq = W1 + (size_t)(r*128)*512;
    Bbase = Xt + ((size_t)(b*8192 + ct2*256))*512;
  } else { int t2 = s - 4; ct = 2*grp + (t2 & 1); hb = t2 >> 1;
    Bbase = Xt + ((size_t)(b*8192 + ct*128))*512;
  }
  if(t < 128) ksum[t] = 0.f;

  f32x4 acc[4][4] = {};

  auto stage = [&](int ks, int cb){
    int goff = ks*32 + pc*8;
    if(isQ){
      ushort* A  = S.buf[cb];            // 128 x 32
      ushort* Bl = S.buf[cb] + 4096;     // 256 x 32
      gload16(Aq    + (size_t)(w*16 + rsub)*512 + goff, A + w*512);
      gload16(Bbase + (size_t)(w*32 + rsub)*512 + goff, Bl + w*1024);
      gload16(Bbase + (size_t)(w*32 + 16 + rsub)*512 + goff, Bl + w*1024 + 512);
    } else {
      ushort* A  = S.buf[cb];            // 256 x 32 (K rows then V rows)
      ushort* Bl = S.buf[cb] + 8192;     // 128 x 32
      int lr0 = w*32 + rsub;
      int gr0 = (w < 4) ? (512 + hb*128 + lr0) : (1024 + hb*128 + (lr0 - 128));
      gload16(W1 + (size_t)gr0*512 + goff, A + w*1024);
      gload16(W1 + (size_t)(gr0 + 16)*512 + goff, A + w*1024 + 512);
      gload16(Bbase + (size_t)(w*16 + rsub)*512 + goff, Bl + w*512);
    }
  };

  auto compute = [&](int cb){
    const ushort *A, *Bl; int aw, bw;
    if(isQ){ A = S.buf[cb]; Bl = S.buf[cb] + 4096; aw = w >> 2; bw = w & 3; }
    else   { A = S.buf[cb]; Bl = S.buf[cb] + 8192; aw = w >> 1; bw = w & 1; }
    int g = lane >> 4;
    short8 af[4], bf[4];
#pragma unroll
    for(int m4 = 0; m4 < 4; ++m4){ int ra = aw*64 + m4*16 + (lane & 15);
      af[m4] = *(const short8*)&A[ra*32 + (g ^ ((ra >> 1) & 3))*8]; }
#pragma unroll
    for(int n4 = 0; n4 < 4; ++n4){ int rb = bw*64 + n4*16 + (lane & 15);
      bf[n4] = *(const short8*)&Bl[rb*32 + (g ^ ((rb >> 1) & 3))*8]; }
#pragma unroll
    for(int m4 = 0; m4 < 4; ++m4)
#pragma unroll
      for(int n4 = 0; n4 < 4; ++n4)
        acc[m4][n4] = __builtin_amdgcn_mfma_f32_16x16x32_bf16(af[m4], bf[n4], acc[m4][n4], 0,0,0);
  };

  // 2-phase double-buffered main loop, counted vmcnt (3 loads/thread/stage)
  stage(0, 0);
#pragma unroll
  for(int ks = 0; ks < 16; ++ks){
    int cur = ks & 1;
    if(ks < 15){ stage(ks + 1, cur ^ 1);
                 asm volatile("s_waitcnt vmcnt(3)" ::: "memory"); }
    else       { asm volatile("s_waitcnt vmcnt(0)" ::: "memory"); }
    __builtin_amdgcn_s_barrier();
    compute(cur);
    asm volatile("s_waitcnt lgkmcnt(0)" ::: "memory");
    __builtin_amdgcn_s_barrier();
  }

  if(isQ){
    int wr = w >> 2, wc = w & 3;
    float cs[4];
    const float* invb = invnorm + b*8192 + ct2*256;
#pragma unroll
    for(int n4 = 0; n4 < 4; ++n4) cs[n4] = invb[wc*64 + n4*16 + (lane & 15)];
    // softmax over this wave's head (64 rows), in registers
    float mx[4] = {-3e38f,-3e38f,-3e38f,-3e38f};
#pragma unroll
    for(int m4 = 0; m4 < 4; ++m4)
#pragma unroll
      for(int n4 = 0; n4 < 4; ++n4)
#pragma unroll
        for(int j = 0; j < 4; ++j){
          float v = acc[m4][n4][j]*cs[n4];
          acc[m4][n4][j] = v;
          mx[n4] = fmaxf(mx[n4], v);
        }
#pragma unroll
    for(int n4 = 0; n4 < 4; ++n4){
      mx[n4] = fmaxf(mx[n4], __shfl_xor(mx[n4], 16));
      mx[n4] = fmaxf(mx[n4], __shfl_xor(mx[n4], 32));
    }
    float sm[4] = {0.f,0.f,0.f,0.f};
#pragma unroll
    for(int m4 = 0; m4 < 4; ++m4)
#pragma unroll
      for(int n4 = 0; n4 < 4; ++n4)
#pragma unroll
        for(int j = 0; j < 4; ++j){
          float e = __expf(acc[m4][n4][j] - mx[n4]);
          acc[m4][n4][j] = e;
          sm[n4] += e;
        }
    float inv[4];
#pragma unroll
    for(int n4 = 0; n4 < 4; ++n4){
      sm[n4] += __shfl_xor(sm[n4], 16);
      sm[n4] += __shfl_xor(sm[n4], 32);
      inv[n4] = 0.125f / sm[n4];             // * dh^-0.5
    }
#pragma unroll
    for(int n4 = 0; n4 < 4; ++n4){
      int col = ct2*256 + wc*64 + n4*16 + (lane & 15);
      ushort* dst = Qt + ((size_t)(b*8192 + col))*512 + r*128 + wr*64 + (lane >> 4)*4;
#pragma unroll
      for(int m4 = 0; m4 < 4; ++m4){
        short4v p;
#pragma unroll
        for(int j = 0; j < 4; ++j) p[j] = (short)f2bf(acc[m4][n4][j]*inv[n4]);
        *(short4v*)(dst + m4*16) = p;
      }
    }
  } else {
    // ---- KV epilogue: exp(K)->P, V->Vb in two 64-l passes; ctx = P @ Vb^T ----
    int wr2 = w >> 1, bw = w & 1;
    bool isK = (w < 4);
    float cs[4];
    const float* invb = invnorm + b*8192 + ct*128;
#pragma unroll
    for(int n4 = 0; n4 < 4; ++n4) cs[n4] = invb[bw*64 + n4*16 + (lane & 15)];
    int hq = w >> 2, rq = w & 3;
    f32x4 c2[4] = {};
#pragma unroll
    for(int hl = 0; hl < 2; ++hl){
      __syncthreads();
      if(bw == hl){
#pragma unroll
        for(int m4 = 0; m4 < 4; ++m4)
#pragma unroll
          for(int j = 0; j < 4; ++j){
            int row = wr2*64 + m4*16 + (lane >> 4)*4 + j;    // 0..255
            float rs = 0.f;
#pragma unroll
            for(int n4 = 0; n4 < 4; ++n4){
              int lc = n4*16 + (lane & 15);                  // local l 0..63
              float val = acc[m4][n4][j]*cs[n4];
              if(isK){
                float e = __expf(val); rs += e;
                S.e.P[row*64 + ((lc >> 3) ^ (row & 7))*8 + (lc & 7)] = f2bf(e);
              } else {
                int er = row - 128;
                S.e.Vb[er*64 + ((lc >> 3) ^ (er & 7))*8 + (lc & 7)] = f2bf(val);
              }
            }
            if(isK) atomicAdd(&ksum[row], rs);
          }
      }
      __syncthreads();
#pragma unroll
      for(int kk = 0; kk < 2; ++kk){
        int g2 = kk*4 + (lane >> 4);
        int da = hq*64 + rq*16 + (lane & 15);
        short8 pa = *(const short8*)&S.e.P[da*64 + (g2 ^ (da & 7))*8];
#pragma unroll
        for(int n4 = 0; n4 < 4; ++n4){
          int eb = hq*64 + n4*16 + (lane & 15);
          short8 vb = *(const short8*)&S.e.Vb[eb*64 + (g2 ^ (eb & 7))*8];
          c2[n4] = __builtin_amdgcn_mfma_f32_16x16x32_bf16(pa, vb, c2[n4], 0,0,0);
        }
      }
    }
    if(t < 128) kpart[(size_t)ct*4096 + b*512 + hb*128 + t] = ksum[t];
    float* dst = ctxp + ((size_t)((b*8 + hb*2 + hq)*64 + ct))*4096;
#pragma unroll
    for(int n4 = 0; n4 < 4; ++n4)
#pragma unroll
      for(int j = 0; j < 4; ++j){
        int d64 = rq*16 + (lane >> 4)*4 + j;
        int e   = n4*16 + (lane & 15);
        dst[d64*64 + e] = c2[n4][j];
      }
  }
}

// ---------------- K2: invZ[row] = 1 / sum_ct kpart[ct][row] ------------------------------
__global__ void k_invz(const float* __restrict__ kpart, float* __restrict__ invZ){
  int row = blockIdx.x*256 + threadIdx.x;   // 4096 exact
  float s = 0.f;
  for(int c = 0; c < 64; ++c) s += kpart[(size_t)c*4096 + row];
  invZ[row] = 1.f / s;
}

// ---------------- K3b: reduce ctx partials (64 ct), scale by invZ, fold W_out ------------
__global__ void k_m2(const float* __restrict__ ctxp, const float* __restrict__ invZ,
                     const float* __restrict__ Wout, ushort* __restrict__ M2){
  __shared__ __align__(16) ushort ctxl[4096]; // chunked [g=e/8][d][8]
  int bh = blockIdx.x, b = bh >> 3, h = bh & 7;
  int t = threadIdx.x, lane = t & 63, w = t >> 6;  // 512 threads, 8 waves
  for(int i = t; i < 4096; i += 512){
    float s = 0.f;
    for(int sp = 0; sp < 64; ++sp) s += ctxp[((size_t)(bh*64 + sp))*4096 + i];
    int d = i >> 6, e = i & 63;
    s *= invZ[bh*64 + d];
    ctxl[(e >> 3)*512 + d*8 + (e & 7)] = f2bf(s);
  }
  __syncthreads();
  f32x4 acc[4][4] = {};
#pragma unroll
  for(int kk = 0; kk < 2; ++kk){
    int g = kk*4 + (lane >> 4);
    short8 bf[4];
#pragma unroll
    for(int n4 = 0; n4 < 4; ++n4)
      bf[n4] = *(const short8*)&ctxl[g*512 + (n4*16 + (lane & 15))*8];
    int e0 = (lane >> 4)*8 + kk*32;
#pragma unroll
    for(int m4 = 0; m4 < 4; ++m4){
      int o = w*64 + m4*16 + (lane & 15);
      const float* wp = Wout + (size_t)o*512 + h*64 + e0;
      float4 w0 = *(const float4*)(wp);
      float4 w1 = *(const float4*)(wp + 4);
      short8 af;
      af[0]=(short)f2bf(w0.x); af[1]=(short)f2bf(w0.y); af[2]=(short)f2bf(w0.z); af[3]=(short)f2bf(w0.w);
      af[4]=(short)f2bf(w1.x); af[5]=(short)f2bf(w1.y); af[6]=(short)f2bf(w1.z); af[7]=(short)f2bf(w1.w);
#pragma unroll
      for(int n4 = 0; n4 < 4; ++n4)
        acc[m4][n4] = __builtin_amdgcn_mfma_f32_16x16x32_bf16(af, bf[n4], acc[m4][n4], 0,0,0);
    }
  }
  ushort* dst = M2 + (size_t)b*512*512 + h*64;
#pragma unroll
  for(int m4 = 0; m4 < 4; ++m4)
#pragma unroll
    for(int n4 = 0; n4 < 4; ++n4)
#pragma unroll
      for(int j = 0; j < 4; ++j){
        int o = w*64 + m4*16 + (lane >> 4)*4 + j;
        int d = n4*16 + (lane & 15);
        dst[(size_t)o*512 + d] = f2bf(acc[m4][n4][j]);
      }
}

// ---------------- K4: out = rmsnorm(M2_b @ Q + b_out, g2), tall tile 512x64, K=512 --------
__global__ __launch_bounds__(512,2) void k_out(const ushort* __restrict__ M2,
                                               const ushort* __restrict__ Qt,
                                               const float* __restrict__ bout,
                                               const float* __restrict__ g2,
                                               float* __restrict__ out){
  __shared__ __align__(16) ushort A[16384];  // 512 rows x 32 elems = 32 KiB
  __shared__ __align__(16) ushort Bs[2048];  // 64 rows x 32 elems
  __shared__ float colss[64];
  __shared__ float bo[512], gg[512];
  int bid = blockIdx.x;                      // 1024
  int wg = (bid & 7)*128 + (bid >> 3);       // XCD-contiguous per batch
  int b = wg >> 7, lb = wg & 127;
  int t = threadIdx.x, lane = t & 63, w = t >> 6;  // 8 waves
  bo[t & 511] = bout[t & 511];
  gg[t & 511] = g2[t & 511];
  if(t < 64) colss[t] = 0.f;
  const ushort* Abase = M2 + (size_t)b*262144;
  const ushort* Bbase = Qt + ((size_t)(b*8192 + lb*64))*512;
  int rsub = lane >> 2;                      // 0..15 (row within 16-row group)
  int pc   = (lane & 3) ^ ((lane >> 3) & 3); // pre-swizzled source chunk
  f32x4 acc[4][4] = {};
  for(int ks = 0; ks < 16; ++ks){
    int goff = ks*32 + pc*8;
#pragma unroll
    for(int j = 0; j < 4; ++j){
      int m = w*4 + j;                       // 0..31, 16 rows each
      gload16(Abase + (size_t)(m*16 + rsub)*512 + goff, &A[m*512]);
    }
    if(w >= 4){
      int m = w - 4;                         // 0..3, 16 rows each
      gload16(Bbase + (size_t)(m*16 + rsub)*512 + goff, &Bs[m*512]);
    }
    __syncthreads();
    int g = lane >> 4;
    short8 bf[4];
#pragma unroll
    for(int n4 = 0; n4 < 4; ++n4){
      int rb = n4*16 + (lane & 15);
      bf[n4] = *(const short8*)&Bs[rb*32 + (g ^ ((rb >> 1) & 3))*8];
    }
#pragma unroll
    for(int m4 = 0; m4 < 4; ++m4){
      int ra = w*64 + m4*16 + (lane & 15);
      short8 af = *(const short8*)&A[ra*32 + (g ^ ((ra >> 1) & 3))*8];
#pragma unroll
      for(int n4 = 0; n4 < 4; ++n4)
        acc[m4][n4] = __builtin_amdgcn_mfma_f32_16x16x32_bf16(af, bf[n4], acc[m4][n4], 0,0,0);
    }
    __syncthreads();
  }
  // bias + column sumsq
  float ps[4] = {0.f,0.f,0.f,0.f};
#pragma unroll
  for(int m4 = 0; m4 < 4; ++m4)
#pragma unroll
    for(int j = 0; j < 4; ++j){
      int o = w*64 + m4*16 + (lane >> 4)*4 + j;
      float bb = bo[o];
#pragma unroll
      for(int n4 = 0; n4 < 4; ++n4){
        float v = acc[m4][n4][j] + bb;
        acc[m4][n4][j] = v;
        ps[n4] += v*v;
      }
    }
#pragma unroll
  for(int n4 = 0; n4 < 4; ++n4) atomicAdd(&colss[n4*16 + (lane & 15)], ps[n4]);
  __syncthreads();
  float csc[4];
#pragma unroll
  for(int n4 = 0; n4 < 4; ++n4)
    csc[n4] = SQRT512 / fmaxf(sqrtf(colss[n4*16 + (lane & 15)]), 1e-12f);
  float* obase = out + ((size_t)b*512)*8192 + lb*64;
#pragma unroll
  for(int m4 = 0; m4 < 4; ++m4)
#pragma unroll
    for(int j = 0; j < 4; ++j){
      int o = w*64 + m4*16 + (lane >> 4)*4 + j;
      float gv = gg[o];
#pragma unroll
      for(int n4 = 0; n4 < 4; ++n4)
        obase[(size_t)o*8192 + n4*16 + (lane & 15)] = acc[m4][n4][j]*csc[n4]*gv;
    }
}

extern "C" void kernel_launch(void* const* d_in, const int* in_sizes, int n_in,
                              void* d_out, int out_size, void* d_ws, size_t ws_size,
                              hipStream_t stream){
  const float* x    = (const float*)d_in[0];
  const float* g1   = (const float*)d_in[1];
  const float* wqkv = (const float*)d_in[2];
  const float* wout = (const float*)d_in[3];
  const float* bout = (const float*)d_in[4];
  const float* g2   = (const float*)d_in[5];
  float* out = (float*)d_out;
  char* ws = (char*)d_ws;
  const size_t MB = 1024*1024;
  ushort* Qt      = (ushort*)(ws);              // 64 MiB  [b][l][512]
  float*  ctxp    = (float*) (ws + 64*MB);      // 67 MiB  [bh][ct][64][64] f32
  ushort* W1      = (ushort*)(ws + 132*MB);     // 1.5 MiB
  float*  invnorm = (float*) (ws + 134*MB);     // 256 KiB
  float*  kpart   = (float*) (ws + 135*MB);     // 1 MiB [64 ct][4096 rows]
  float*  invZ    = (float*) (ws + 136*MB);     // 16 KiB
  ushort* M2      = (ushort*)(ws + 137*MB);     // 4 MiB  [b][512][512]
  // d_out doubles as scratch until k_out: Xt in first half
  ushort* Xt = (ushort*)d_out;

  k_prep_w1<<<3072, 256, 0, stream>>>(wqkv, g1, W1);
  k_xt<<<dim3(128, 8), 256, 0, stream>>>(x, Xt, invnorm);
  k_qkv<<<3072, 512, 0, stream>>>(W1, Xt, invnorm, Qt, ctxp, kpart);
  k_invz<<<16, 256, 0, stream>>>(kpart, invZ);
  k_m2<<<64, 512, 0, stream>>>(ctxp, invZ, wout, M2);
  k_out<<<1024, 512, 0, stream>>>(M2, Qt, bout, g2, out);
}

// Round 6
// 397.953 us; speedup vs baseline: 1.0124x; 1.0124x over previous
//
#include <hip/hip_runtime.h>
#include <hip/hip_bf16.h>

// LinearAttention fused pipeline for MI355X (gfx950), bf16 MFMA.
// B=8, C=512, L=8192, H=8, DH=64, HID=512, M1=3*HID=1536.
// R5: fix R4's staging race — counted vmcnt moved to the K-tile boundary
// (before the boundary barrier), per the verified 8-phase template.

typedef short short8 __attribute__((ext_vector_type(8)));
typedef short short4v __attribute__((ext_vector_type(4)));
typedef float f32x4 __attribute__((ext_vector_type(4)));
typedef unsigned short ushort;

#define SQRT512 22.627416997969522f

__device__ __forceinline__ ushort f2bf(float f){
  union{float f; unsigned u;} v; v.f = f;
  unsigned r = v.u + 0x7fffu + ((v.u >> 16) & 1u);
  return (ushort)(r >> 16);
}

// async global->LDS, 16B per lane; lds dest is wave-uniform base (HW adds lane*16)
__device__ __forceinline__ void gload16(const void* g, void* l){
  __builtin_amdgcn_global_load_lds(
      (const __attribute__((address_space(1))) unsigned int*)(unsigned long long)g,
      (__attribute__((address_space(3))) unsigned int*)(unsigned int)(unsigned long long)l,
      16, 0, 0);
}

// ---------------- K0b: W1[o][c] = w_qkv[o][c] * g1[c] * sqrt(512)  (bf16) ----------------
__global__ void k_prep_w1(const float* __restrict__ wqkv, const float* __restrict__ g1,
                          ushort* __restrict__ W1){
  int i = blockIdx.x * 256 + threadIdx.x;   // 1536*512 exact
  int c = i & 511;
  W1[i] = f2bf(wqkv[i] * g1[c] * SQRT512);
}

// ---------------- K0: transpose x -> Xt[b][l][c] bf16, and invnorm[b][l] ------------------
__global__ __launch_bounds__(256) void k_xt(const float* __restrict__ x,
                                            ushort* __restrict__ Xt,
                                            float* __restrict__ invnorm){
  __shared__ __align__(16) ushort tile[64*132]; // 64 l-rows x 128 c, pitch 132
  __shared__ float ssq[4][64];
  int b = blockIdx.y, lb = blockIdx.x;
  int t = threadIdx.x, lane = t & 63, crow = t >> 6;
  const float* xb = x + ((size_t)b*512)*8192 + (size_t)lb*64;
  float acc = 0.f;
  for(int c0 = 0; c0 < 512; c0 += 128){
    __syncthreads();
    for(int cc = crow; cc < 128; cc += 4){
      float v = xb[(size_t)(c0+cc)*8192 + lane];
      acc += v*v;
      tile[lane*132 + cc] = f2bf(v);
    }
    __syncthreads();
    ushort* dst = Xt + ((size_t)(b*8192 + lb*64))*512 + c0;
    int ch = t & 31;
    for(int r = t >> 5; r < 64; r += 8){
      short4v vv = *(const short4v*)&tile[r*132 + ch*4];
      *(short4v*)(dst + (size_t)r*512 + ch*4) = vv;
    }
  }
  ssq[crow][lane] = acc;
  __syncthreads();
  if(t < 64){
    float s = ssq[0][t] + ssq[1][t] + ssq[2][t] + ssq[3][t];
    invnorm[b*8192 + lb*64 + t] = 1.f / fmaxf(sqrtf(s), 1e-12f);
  }
}

// ---------------- K1: QKV GEMM, 256x256 tile, 8-phase pipelined ---------------------------
// 512 threads / 8 waves (2M x 4N). K=512 -> 8 K-tiles of BK=64.
// LDS: A slots [db][mh] (128rows x 64) @0, B slots [db][nh] @32768; 128 KiB.
// Per phase q: {12 ds_read + 1 half-tile stage} -> barrier -> 16 MFMA (setprio)
// -> [K-tile boundary only: vmcnt(4)] -> barrier.
// Epilogue by mt: 0-1 Q softmax -> Qt; 2-3 exp(K)+rowsums -> EK; 4-5 V.
__global__ __launch_bounds__(512,2) void k_qkv(
    const ushort* __restrict__ W1, const ushort* __restrict__ Xt,
    const float* __restrict__ invnorm,
    ushort* __restrict__ Qt, ushort* __restrict__ EK, ushort* __restrict__ V,
    float* __restrict__ kpart){
  __shared__ __align__(16) union {
    ushort pipe[65536];        // 128 KiB pipeline buffers
    ushort T[128*264];         // epilogue restage tile (67.5 KiB)
  } S;
  __shared__ float ksum[256];

  int bid = blockIdx.x;                   // 1536
  int wg  = (bid & 7)*192 + (bid >> 3);   // one batch per XCD; 6-block panel groups
  int b   = wg / 192;
  int rem = wg % 192;
  int nt  = rem / 6, mt = rem % 6;        // nt-major: consecutive mt share Xt panel
  int t = threadIdx.x, lane = t & 63, w = t >> 6;
  int wr = w >> 2, wc = w & 3;            // 2 x 4 wave grid
  int lc = (t & 7) ^ ((t >> 3) & 7);      // staging logical chunk (XOR swizzle)
  const ushort* Xtb = Xt + (size_t)b*8192*512;

  if(t < 256) ksum[t] = 0.f;

  f32x4 acc[8][4] = {};

  auto stageA = [&](int tt, int mh){
    ushort* dst = &S.pipe[((tt&1)*2 + mh)*8192 + w*512];
#pragma unroll
    for(int i = 0; i < 2; ++i){
      int grow = mt*256 + i*128 + mh*64 + (t >> 3);
      gload16(W1 + (size_t)grow*512 + tt*64 + lc*8, dst + i*4096);
    }
  };
  auto stageB = [&](int tt, int nh){
    ushort* dst = &S.pipe[32768 + ((tt&1)*2 + nh)*8192 + w*512];
#pragma unroll
    for(int i = 0; i < 2; ++i){
      int rl = i*64 + (t >> 3);
      int gcol = nt*256 + (rl >> 5)*64 + nh*32 + (rl & 31);
      gload16(Xtb + (size_t)gcol*512 + tt*64 + lc*8, dst + i*4096);
    }
  };

  // prologue: kt0 fully + kt1 h0 halves, then guarantee kt0 (8 instr done, 4 in flight)
  stageA(0,0); stageB(0,0); stageA(0,1); stageB(0,1); stageA(1,0); stageB(1,0);
  asm volatile("s_waitcnt vmcnt(4)" ::: "memory");
  __builtin_amdgcn_s_barrier();

  for(int kt = 0; kt < 8; ++kt){
    int db = kt & 1;
#pragma unroll
    for(int q = 0; q < 4; ++q){
      const int mh = q >> 1, nh = q & 1;
      const ushort* As = &S.pipe[(db*2 + mh)*8192];
      const ushort* Bs = &S.pipe[32768 + (db*2 + nh)*8192];
      short8 af[4][2], bf[2][2];
#pragma unroll
      for(int m16 = 0; m16 < 4; ++m16){
        int ra = wr*64 + m16*16 + (lane & 15);
#pragma unroll
        for(int kk = 0; kk < 2; ++kk)
          af[m16][kk] = *(const short8*)&As[ra*64 + ((kk*4 + (lane >> 4)) ^ (ra & 7))*8];
      }
#pragma unroll
      for(int n16 = 0; n16 < 2; ++n16){
        int rb = wc*32 + n16*16 + (lane & 15);
#pragma unroll
        for(int kk = 0; kk < 2; ++kk)
          bf[n16][kk] = *(const short8*)&Bs[rb*64 + ((kk*4 + (lane >> 4)) ^ (rb & 7))*8];
      }
      // rolling half-tile prefetch (target slots are dead: opposite db parity for
      // h1 stages; h0 stages overwrite a slot last read one barrier earlier)
      if(q == 0){ if(kt + 1 < 8) stageA(kt+1, 1); }
      else if(q == 1){ if(kt + 1 < 8) stageB(kt+1, 1); }
      else if(q == 2){ if(kt + 2 < 8) stageA(kt+2, 0); }
      else           { if(kt + 2 < 8) stageB(kt+2, 0); }
      __builtin_amdgcn_s_barrier();
      __builtin_amdgcn_s_setprio(1);
#pragma unroll
      for(int m16 = 0; m16 < 4; ++m16)
#pragma unroll
        for(int n16 = 0; n16 < 2; ++n16)
#pragma unroll
          for(int kk = 0; kk < 2; ++kk)
            acc[mh*4+m16][nh*2+n16] = __builtin_amdgcn_mfma_f32_16x16x32_bf16(
                af[m16][kk], bf[n16][kk], acc[mh*4+m16][nh*2+n16], 0,0,0);
      __builtin_amdgcn_s_setprio(0);
      // K-tile boundary: guarantee next kt's half-tiles BEFORE its ds_reads
      if(q == 3){
        if(kt < 6)      asm volatile("s_waitcnt vmcnt(4)" ::: "memory");
        else if(kt == 6) asm volatile("s_waitcnt vmcnt(0)" ::: "memory");
      }
      __builtin_amdgcn_s_barrier();
    }
  }

  // column scales (1/||x_col||)
  float cs[4];
  const float* invb = invnorm + b*8192 + nt*256;
#pragma unroll
  for(int n = 0; n < 4; ++n) cs[n] = invb[wc*64 + n*16 + (lane & 15)];

  if(mt < 2){
    // ---- Q: per-head softmax over dh=64 rows; wave holds 2 heads (mh 0/1) ----
    float mx[2][4], sm[2][4];
#pragma unroll
    for(int mh = 0; mh < 2; ++mh)
#pragma unroll
      for(int n = 0; n < 4; ++n){ mx[mh][n] = -3e38f; sm[mh][n] = 0.f; }
#pragma unroll
    for(int m = 0; m < 8; ++m)
#pragma unroll
      for(int n = 0; n < 4; ++n)
#pragma unroll
        for(int j = 0; j < 4; ++j){
          float v = acc[m][n][j]*cs[n];
          acc[m][n][j] = v;
          mx[m>>2][n] = fmaxf(mx[m>>2][n], v);
        }
#pragma unroll
    for(int mh = 0; mh < 2; ++mh)
#pragma unroll
      for(int n = 0; n < 4; ++n){
        mx[mh][n] = fmaxf(mx[mh][n], __shfl_xor(mx[mh][n], 16));
        mx[mh][n] = fmaxf(mx[mh][n], __shfl_xor(mx[mh][n], 32));
      }
#pragma unroll
    for(int m = 0; m < 8; ++m)
#pragma unroll
      for(int n = 0; n < 4; ++n)
#pragma unroll
        for(int j = 0; j < 4; ++j){
          float e = __expf(acc[m][n][j] - mx[m>>2][n]);
          acc[m][n][j] = e;
          sm[m>>2][n] += e;
        }
    float inv[2][4];
#pragma unroll
    for(int mh = 0; mh < 2; ++mh)
#pragma unroll
      for(int n = 0; n < 4; ++n){
        sm[mh][n] += __shfl_xor(sm[mh][n], 16);
        sm[mh][n] += __shfl_xor(sm[mh][n], 32);
        inv[mh][n] = 0.125f / sm[mh][n];       // * dh^-0.5
      }
    // write transposed: Qt[b][l][512]
#pragma unroll
    for(int n = 0; n < 4; ++n){
      int col = nt*256 + wc*64 + n*16 + (lane & 15);
      ushort* dst = Qt + ((size_t)(b*8192 + col))*512 + mt*256 + wr*128 + (lane >> 4)*4;
#pragma unroll
      for(int m = 0; m < 8; ++m){
        short4v p;
#pragma unroll
        for(int j = 0; j < 4; ++j) p[j] = (short)f2bf(acc[m][n][j]*inv[m>>2][n]);
        *(short4v*)(dst + m*16) = p;
      }
    }
  } else {
    bool isK = (mt < 4);
    ushort* dstG = isK ? EK : V;
    int mo = isK ? (mt - 2) : (mt - 4);
    if(isK){
      // exp + row sums
#pragma unroll
      for(int m = 0; m < 8; ++m)
#pragma unroll
        for(int n = 0; n < 4; ++n)
#pragma unroll
          for(int j = 0; j < 4; ++j)
            acc[m][n][j] = __expf(acc[m][n][j]*cs[n]);
#pragma unroll
      for(int m = 0; m < 8; ++m)
#pragma unroll
        for(int j = 0; j < 4; ++j){
          float s = acc[m][0][j] + acc[m][1][j] + acc[m][2][j] + acc[m][3][j];
          s += __shfl_xor(s, 1); s += __shfl_xor(s, 2);
          s += __shfl_xor(s, 4); s += __shfl_xor(s, 8);
          if((lane & 15) == 0)
            atomicAdd(&ksum[wr*128 + m*16 + (lane >> 4)*4 + j], s);
        }
      __syncthreads();
      if(t < 256) kpart[(size_t)nt*4096 + b*512 + mo*256 + t] = ksum[t];
    } else {
#pragma unroll
      for(int m = 0; m < 8; ++m)
#pragma unroll
        for(int n = 0; n < 4; ++n)
#pragma unroll
          for(int j = 0; j < 4; ++j)
            acc[m][n][j] = acc[m][n][j]*cs[n];
    }
    // restage through LDS (two 128-row passes) -> coalesced full-line stores
    for(int h = 0; h < 2; ++h){
      __syncthreads();
      if(wr == h){
#pragma unroll
        for(int m = 0; m < 8; ++m)
#pragma unroll
          for(int j = 0; j < 4; ++j){
            int rl = m*16 + (lane >> 4)*4 + j;
#pragma unroll
            for(int n = 0; n < 4; ++n)
              S.T[rl*264 + wc*64 + n*16 + (lane & 15)] = f2bf(acc[m][n][j]);
          }
      }
      __syncthreads();
      int cc = t & 15;
      for(int rr = t >> 4; rr < 128; rr += 32){
        short8 v0 = *(const short8*)&S.T[rr*264 + cc*16];
        short8 v1 = *(const short8*)&S.T[rr*264 + cc*16 + 8];
        ushort* dst = dstG + ((size_t)(b*512 + mo*256 + h*128 + rr))*8192 + nt*256 + cc*16;
        *(short8*)dst = v0;
        *(short8*)(dst + 8) = v1;
      }
    }
  }
}

// ---------------- K2: invZ[row] = 1 / sum_nt kpart[nt][row] ------------------------------
__global__ void k_invz(const float* __restrict__ kpart, float* __restrict__ invZ){
  int row = blockIdx.x*256 + threadIdx.x;   // 4096 exact
  float s = 0.f;
  for(int c = 0; c < 32; ++c) s += kpart[(size_t)c*4096 + row];
  invZ[row] = 1.f / s;
}

// ---------------- K3: ctx partials: EXPK(64xL) @ V(64xL)^T, split-K=16 --------------------
__global__ __launch_bounds__(256,4) void k_ctx(const ushort* __restrict__ EK,
                                               const ushort* __restrict__ V,
                                               float* __restrict__ ctxp){
  __shared__ __align__(16) ushort A[4096];   // 64 rows x 64 elems
  __shared__ __align__(16) ushort Bs[4096];
  int bid = blockIdx.x;                      // 1024 = 64 bh * 16 splits
  int split = bid & 15, bh = bid >> 4;
  int t = threadIdx.x, lane = t & 63, w = t >> 6;
  const ushort* Abase = EK + (size_t)bh*64*8192;
  const ushort* Bbase = V  + (size_t)bh*64*8192;
  int rsub = lane >> 3;
  int pc   = (lane & 7) ^ rsub;
  f32x4 acc[4] = {};
  for(int ks = 0; ks < 8; ++ks){
    int goff = split*512 + ks*64 + pc*8;
#pragma unroll
    for(int j = 0; j < 2; ++j){
      int m = w*2 + j;                       // 0..7, 8 rows each
      gload16(Abase + (size_t)(m*8 + rsub)*8192 + goff, &A[m*512]);
      gload16(Bbase + (size_t)(m*8 + rsub)*8192 + goff, &Bs[m*512]);
    }
    __syncthreads();
#pragma unroll
    for(int kk = 0; kk < 2; ++kk){
      int g = kk*4 + (lane >> 4);
      int ra = w*16 + (lane & 15);
      short8 af = *(const short8*)&A[ra*64 + (g ^ (ra & 7))*8];
#pragma unroll
      for(int n4 = 0; n4 < 4; ++n4){
        int rb = n4*16 + (lane & 15);
        short8 bf = *(const short8*)&Bs[rb*64 + (g ^ (rb & 7))*8];
        acc[n4] = __builtin_amdgcn_mfma_f32_16x16x32_bf16(af, bf, acc[n4], 0,0,0);
      }
    }
    __syncthreads();
  }
  float* dst = ctxp + ((size_t)(bh*16 + split))*4096;
#pragma unroll
  for(int n4 = 0; n4 < 4; ++n4)
#pragma unroll
    for(int j = 0; j < 4; ++j){
      int d = w*16 + (lane >> 4)*4 + j, e = n4*16 + (lane & 15);
      dst[d*64 + e] = acc[n4][j];
    }
}

// ---------------- K3b: reduce ctx partials (16 splits), scale by invZ, fold W_out --------
__global__ void k_m2(const float* __restrict__ ctxp, const float* __restrict__ invZ,
                     const float* __restrict__ Wout, ushort* __restrict__ M2){
  __shared__ __align__(16) ushort ctxl[4096]; // chunked [g=e/8][d][8]
  int bh = blockIdx.x, b = bh >> 3, h = bh & 7;
  int t = threadIdx.x, lane = t & 63, w = t >> 6;  // 512 threads, 8 waves
  for(int i = t; i < 4096; i += 512){
    float s = 0.f;
    for(int sp = 0; sp < 16; ++sp) s += ctxp[((size_t)(bh*16 + sp))*4096 + i];
    int d = i >> 6, e = i & 63;
    s *= invZ[bh*64 + d];
    ctxl[(e >> 3)*512 + d*8 + (e & 7)] = f2bf(s);
  }
  __syncthreads();
  f32x4 acc[4][4] = {};
#pragma unroll
  for(int kk = 0; kk < 2; ++kk){
    int g = kk*4 + (lane >> 4);
    short8 bf[4];
#pragma unroll
    for(int n4 = 0; n4 < 4; ++n4)
      bf[n4] = *(const short8*)&ctxl[g*512 + (n4*16 + (lane & 15))*8];
    int e0 = (lane >> 4)*8 + kk*32;
#pragma unroll
    for(int m4 = 0; m4 < 4; ++m4){
      int o = w*64 + m4*16 + (lane & 15);
      const float* wp = Wout + (size_t)o*512 + h*64 + e0;
      float4 w0 = *(const float4*)(wp);
      float4 w1 = *(const float4*)(wp + 4);
      short8 af;
      af[0]=(short)f2bf(w0.x); af[1]=(short)f2bf(w0.y); af[2]=(short)f2bf(w0.z); af[3]=(short)f2bf(w0.w);
      af[4]=(short)f2bf(w1.x); af[5]=(short)f2bf(w1.y); af[6]=(short)f2bf(w1.z); af[7]=(short)f2bf(w1.w);
#pragma unroll
      for(int n4 = 0; n4 < 4; ++n4)
        acc[m4][n4] = __builtin_amdgcn_mfma_f32_16x16x32_bf16(af, bf[n4], acc[m4][n4], 0,0,0);
    }
  }
  ushort* dst = M2 + (size_t)b*512*512 + h*64;
#pragma unroll
  for(int m4 = 0; m4 < 4; ++m4)
#pragma unroll
    for(int n4 = 0; n4 < 4; ++n4)
#pragma unroll
      for(int j = 0; j < 4; ++j){
        int o = w*64 + m4*16 + (lane >> 4)*4 + j;
        int d = n4*16 + (lane & 15);
        dst[(size_t)o*512 + d] = f2bf(acc[m4][n4][j]);
      }
}

// ---------------- K4: out = rmsnorm(M2_b @ Q + b_out, g2), tall tile 512x64, K=512 --------
__global__ __launch_bounds__(512,2) void k_out(const ushort* __restrict__ M2,
                                               const ushort* __restrict__ Qt,
                                               const float* __restrict__ bout,
                                               const float* __restrict__ g2,
                                               float* __restrict__ out){
  __shared__ __align__(16) ushort A[16384];  // 512 rows x 32 elems = 32 KiB
  __shared__ __align__(16) ushort Bs[2048];  // 64 rows x 32 elems
  __shared__ float colss[64];
  __shared__ float bo[512], gg[512];
  int bid = blockIdx.x;                      // 1024
  int wg = (bid & 7)*128 + (bid >> 3);       // XCD-contiguous per batch
  int b = wg >> 7, lb = wg & 127;
  int t = threadIdx.x, lane = t & 63, w = t >> 6;  // 8 waves
  bo[t & 511] = bout[t & 511];
  gg[t & 511] = g2[t & 511];
  if(t < 64) colss[t] = 0.f;
  const ushort* Abase = M2 + (size_t)b*262144;
  const ushort* Bbase = Qt + ((size_t)(b*8192 + lb*64))*512;
  int rsub = lane >> 2;                      // 0..15 (row within 16-row group)
  int pc   = (lane & 3) ^ ((lane >> 3) & 3); // pre-swizzled source chunk
  f32x4 acc[4][4] = {};
  for(int ks = 0; ks < 16; ++ks){
    int goff = ks*32 + pc*8;
#pragma unroll
    for(int j = 0; j < 4; ++j){
      int m = w*4 + j;                       // 0..31, 16 rows each
      gload16(Abase + (size_t)(m*16 + rsub)*512 + goff, &A[m*512]);
    }
    if(w >= 4){
      int m = w - 4;                         // 0..3, 16 rows each
      gload16(Bbase + (size_t)(m*16 + rsub)*512 + goff, &Bs[m*512]);
    }
    __syncthreads();
    int g = lane >> 4;
    short8 bf[4];
#pragma unroll
    for(int n4 = 0; n4 < 4; ++n4){
      int rb = n4*16 + (lane & 15);
      bf[n4] = *(const short8*)&Bs[rb*32 + (g ^ ((rb >> 1) & 3))*8];
    }
#pragma unroll
    for(int m4 = 0; m4 < 4; ++m4){
      int ra = w*64 + m4*16 + (lane & 15);
      short8 af = *(const short8*)&A[ra*32 + (g ^ ((ra >> 1) & 3))*8];
#pragma unroll
      for(int n4 = 0; n4 < 4; ++n4)
        acc[m4][n4] = __builtin_amdgcn_mfma_f32_16x16x32_bf16(af, bf[n4], acc[m4][n4], 0,0,0);
    }
    __syncthreads();
  }
  // bias + column sumsq
  float ps[4] = {0.f,0.f,0.f,0.f};
#pragma unroll
  for(int m4 = 0; m4 < 4; ++m4)
#pragma unroll
    for(int j = 0; j < 4; ++j){
      int o = w*64 + m4*16 + (lane >> 4)*4 + j;
      float bb = bo[o];
#pragma unroll
      for(int n4 = 0; n4 < 4; ++n4){
        float v = acc[m4][n4][j] + bb;
        acc[m4][n4][j] = v;
        ps[n4] += v*v;
      }
    }
#pragma unroll
  for(int n4 = 0; n4 < 4; ++n4) atomicAdd(&colss[n4*16 + (lane & 15)], ps[n4]);
  __syncthreads();
  float csc[4];
#pragma unroll
  for(int n4 = 0; n4 < 4; ++n4)
    csc[n4] = SQRT512 / fmaxf(sqrtf(colss[n4*16 + (lane & 15)]), 1e-12f);
  float* obase = out + ((size_t)b*512)*8192 + lb*64;
#pragma unroll
  for(int m4 = 0; m4 < 4; ++m4)
#pragma unroll
    for(int j = 0; j < 4; ++j){
      int o = w*64 + m4*16 + (lane >> 4)*4 + j;
      float gv = gg[o];
#pragma unroll
      for(int n4 = 0; n4 < 4; ++n4)
        obase[(size_t)o*8192 + n4*16 + (lane & 15)] = acc[m4][n4][j]*csc[n4]*gv;
    }
}

extern "C" void kernel_launch(void* const* d_in, const int* in_sizes, int n_in,
                              void* d_out, int out_size, void* d_ws, size_t ws_size,
                              hipStream_t stream){
  const float* x    = (const float*)d_in[0];
  const float* g1   = (const float*)d_in[1];
  const float* wqkv = (const float*)d_in[2];
  const float* wout = (const float*)d_in[3];
  const float* bout = (const float*)d_in[4];
  const float* g2   = (const float*)d_in[5];
  float* out = (float*)d_out;
  char* ws = (char*)d_ws;
  const size_t MB = 1024*1024;
  ushort* Qt      = (ushort*)(ws);              // 64 MiB  [b][l][512]
  ushort* EK      = (ushort*)(ws + 64*MB);      // 64 MiB  [b][512][l]
  ushort* W1      = (ushort*)(ws + 128*MB);     // 1.5 MiB
  float*  invnorm = (float*) (ws + 130*MB);     // 256 KiB
  float*  kpart   = (float*) (ws + 131*MB);     // 512 KiB [32 nt][4096 rows]
  float*  invZ    = (float*) (ws + 132*MB);     // 16 KiB
  float*  ctxp    = (float*) (ws + 133*MB);     // 16 MiB [64 bh][16][64][64]
  ushort* M2      = (ushort*)(ws + 149*MB);     // 4 MiB  [b][512][512]
  // d_out doubles as scratch until k_out: Xt in first half, V in second half
  ushort* Xt = (ushort*)d_out;
  ushort* V  = (ushort*)((char*)d_out + 64*MB);

  k_prep_w1<<<3072, 256, 0, stream>>>(wqkv, g1, W1);
  k_xt<<<dim3(128, 8), 256, 0, stream>>>(x, Xt, invnorm);
  k_qkv<<<1536, 512, 0, stream>>>(W1, Xt, invnorm, Qt, EK, V, kpart);
  k_invz<<<16, 256, 0, stream>>>(kpart, invZ);
  k_ctx<<<1024, 256, 0, stream>>>(EK, V, ctxp);
  k_m2<<<64, 512, 0, stream>>>(ctxp, invZ, wout, M2);
  k_out<<<1024, 512, 0, stream>>>(M2, Qt, bout, g2, out);
}